// Round 1
// baseline (1312.819 us; speedup 1.0000x reference)
//
#include <hip/hip_runtime.h>
#include <hip/hip_bf16.h>

// ---------- types ----------
typedef float f32x4 __attribute__((ext_vector_type(4)));
typedef short short8 __attribute__((ext_vector_type(8)));
typedef unsigned short ushort8 __attribute__((ext_vector_type(8)));
typedef unsigned short ushort4v __attribute__((ext_vector_type(4)));

static __device__ __forceinline__ unsigned short f2bf(float f) {
  // round-to-nearest-even f32 -> bf16 (finite inputs only)
  unsigned u = __builtin_bit_cast(unsigned, f);
  u += 0x7fffu + ((u >> 16) & 1u);
  return (unsigned short)(u >> 16);
}
static __device__ __forceinline__ float bf2f(unsigned short s) {
  return __builtin_bit_cast(float, (unsigned)s << 16);
}

// ---------- 1. f32 -> bf16 convert (x) ----------
__global__ __launch_bounds__(256) void k_cvt_bf16(const float* __restrict__ in,
                                                  unsigned short* __restrict__ out,
                                                  int n8) {
  int i = blockIdx.x * 256 + threadIdx.x;
  if (i >= n8) return;
  const float4* p = (const float4*)in + (size_t)i * 2;
  float4 a = p[0], b = p[1];
  ushort8 o;
  o[0] = f2bf(a.x); o[1] = f2bf(a.y); o[2] = f2bf(a.z); o[3] = f2bf(a.w);
  o[4] = f2bf(b.x); o[5] = f2bf(b.y); o[6] = f2bf(b.z); o[7] = f2bf(b.w);
  *(ushort8*)(out + (size_t)i * 8) = o;
}

// ---------- 2. f32 [R][C] -> bf16 [C][R] transpose+convert ----------
__global__ __launch_bounds__(256) void k_transpose_cvt(const float* __restrict__ in,
                                                       unsigned short* __restrict__ out,
                                                       int R, int C) {
  __shared__ float tile[64][65];  // +1 pad breaks bank conflicts
  int c0 = blockIdx.x * 64;
  int r0 = blockIdx.y * 64;
  int t = threadIdx.x;
  int tr = t >> 4;          // 0..15
  int tc = (t & 15) << 2;   // 0..60
  for (int i = 0; i < 4; ++i) {
    int r = tr + (i << 4);
    float4 v = *(const float4*)&in[(size_t)(r0 + r) * C + c0 + tc];
    tile[r][tc] = v.x; tile[r][tc + 1] = v.y; tile[r][tc + 2] = v.z; tile[r][tc + 3] = v.w;
  }
  __syncthreads();
  for (int i = 0; i < 4; ++i) {
    int c = tr + (i << 4);  // output row (original column)
    ushort4v o;
    o[0] = f2bf(tile[tc + 0][c]);
    o[1] = f2bf(tile[tc + 1][c]);
    o[2] = f2bf(tile[tc + 2][c]);
    o[3] = f2bf(tile[tc + 3][c]);
    *(ushort4v*)&out[(size_t)(c0 + c) * R + r0 + tc] = o;  // 8B aligned store
  }
}

// ---------- 3. bf16 GEMM, m97 structure: 128x128 tile, BK=32, 4 waves ----------
// A:  M x K   bf16 row-major (k contiguous)
// Bt: N x K   bf16 row-major (k contiguous)  == B^T
// out[m][n] = sum_k A[m][k]*Bt[n][k] + D[m][n]; OUT_BF16 selects store dtype
template <int OUT_BF16>
__global__ __launch_bounds__(256) void k_gemm(const unsigned short* __restrict__ A,
                                              const unsigned short* __restrict__ Bt,
                                              const float* __restrict__ D,
                                              void* __restrict__ out,
                                              int M, int N, int K) {
  constexpr int BM = 128, BN = 128, BK = 32;
  __shared__ unsigned short As[BM * BK];
  __shared__ unsigned short Bs[BN * BK];

  // bijective XCD swizzle (grid divisible by 8 here)
  int nwg = gridDim.x;
  int bid = blockIdx.x;
  int cpx = nwg >> 3;
  int swz = (bid & 7) * cpx + (bid >> 3);
  int nbn = N / BN;
  int bm0 = (swz / nbn) * BM;
  int bn0 = (swz % nbn) * BN;

  int t = threadIdx.x;
  int lane = t & 63;
  int w = t >> 6;
  int wm = (w >> 1) << 6;  // wave 2x2 over the 128x128 tile
  int wn = (w & 1) << 6;

  // staging: thread t covers tile row t/4, k-offset (t%4)*8 (16B), linear LDS dest
  const unsigned short* gA = A + (size_t)(bm0 + (t >> 2)) * K + ((t & 3) << 3);
  const unsigned short* gB = Bt + (size_t)(bn0 + (t >> 2)) * K + ((t & 3) << 3);
  unsigned short* ldsA = As + t * 8;
  unsigned short* ldsB = Bs + t * 8;

  f32x4 acc[4][4];
  for (int i = 0; i < 4; ++i)
    for (int j = 0; j < 4; ++j)
      acc[i][j] = f32x4{0.f, 0.f, 0.f, 0.f};

  int row = lane & 15;
  int ks = (lane >> 4) << 3;  // k-slice start for this lane group
  const int nk = K >> 5;      // K / BK

  for (int kt = 0; kt < nk; ++kt) {
    __builtin_amdgcn_global_load_lds((const __attribute__((address_space(1))) void*)gA,
                                     (__attribute__((address_space(3))) void*)ldsA, 16, 0, 0);
    __builtin_amdgcn_global_load_lds((const __attribute__((address_space(1))) void*)(gA + (size_t)64 * K),
                                     (__attribute__((address_space(3))) void*)(ldsA + 2048), 16, 0, 0);
    __builtin_amdgcn_global_load_lds((const __attribute__((address_space(1))) void*)gB,
                                     (__attribute__((address_space(3))) void*)ldsB, 16, 0, 0);
    __builtin_amdgcn_global_load_lds((const __attribute__((address_space(1))) void*)(gB + (size_t)64 * K),
                                     (__attribute__((address_space(3))) void*)(ldsB + 2048), 16, 0, 0);
    gA += BK;
    gB += BK;
    __syncthreads();  // drains vmcnt -> LDS tiles ready

    short8 af[4], bfr[4];
    for (int i = 0; i < 4; ++i)
      af[i] = *(const short8*)&As[(wm + (i << 4) + row) * BK + ks];
    for (int j = 0; j < 4; ++j)
      bfr[j] = *(const short8*)&Bs[(wn + (j << 4) + row) * BK + ks];
    for (int i = 0; i < 4; ++i)
      for (int j = 0; j < 4; ++j)
        acc[i][j] = __builtin_amdgcn_mfma_f32_16x16x32_bf16(af[i], bfr[j], acc[i][j], 0, 0, 0);
    __syncthreads();  // protect LDS before next iteration's staging
  }

  // epilogue: + D, store (C/D layout: col=lane&15, row=(lane>>4)*4+reg)
  int r0 = bm0 + wm + ((lane >> 4) << 2);
  int cc = bn0 + wn + (lane & 15);
  for (int i = 0; i < 4; ++i) {
    for (int j = 0; j < 4; ++j) {
      int rbase = r0 + (i << 4);
      int c = cc + (j << 4);
      for (int rr = 0; rr < 4; ++rr) {
        size_t idx = (size_t)(rbase + rr) * N + c;
        float v = acc[i][j][rr] + D[idx];
        if (OUT_BF16)
          ((unsigned short*)out)[idx] = f2bf(v);
        else
          ((float*)out)[idx] = v;
      }
    }
  }
}

// ---------- 4. row RMSNorm in-place on bf16 h, scale by g ----------
__global__ __launch_bounds__(256) void k_rmsnorm(unsigned short* __restrict__ h,
                                                 const float* __restrict__ g,
                                                 int N) {
  __shared__ float red[4];
  int rowi = blockIdx.x;
  unsigned short* p = h + (size_t)rowi * N;
  int t = threadIdx.x;
  int base = t << 4;  // 16 elements per thread, N = 4096 = 256*16
  ushort8 v0 = *(const ushort8*)&p[base];
  ushort8 v1 = *(const ushort8*)&p[base + 8];
  float f[16];
  float ss = 0.f;
  for (int j = 0; j < 8; ++j) { f[j] = bf2f(v0[j]); ss += f[j] * f[j]; }
  for (int j = 0; j < 8; ++j) { f[8 + j] = bf2f(v1[j]); ss += f[8 + j] * f[8 + j]; }
  for (int off = 32; off > 0; off >>= 1) ss += __shfl_xor(ss, off);
  if ((t & 63) == 0) red[t >> 6] = ss;
  __syncthreads();
  float total = red[0] + red[1] + red[2] + red[3];
  float scale = rsqrtf(total / (float)N + 1e-6f);
  float4 g0 = *(const float4*)&g[base];
  float4 g1 = *(const float4*)&g[base + 4];
  float4 g2 = *(const float4*)&g[base + 8];
  float4 g3 = *(const float4*)&g[base + 12];
  ushort8 o0, o1;
  o0[0] = f2bf(f[0] * scale * g0.x);  o0[1] = f2bf(f[1] * scale * g0.y);
  o0[2] = f2bf(f[2] * scale * g0.z);  o0[3] = f2bf(f[3] * scale * g0.w);
  o0[4] = f2bf(f[4] * scale * g1.x);  o0[5] = f2bf(f[5] * scale * g1.y);
  o0[6] = f2bf(f[6] * scale * g1.z);  o0[7] = f2bf(f[7] * scale * g1.w);
  o1[0] = f2bf(f[8] * scale * g2.x);  o1[1] = f2bf(f[9] * scale * g2.y);
  o1[2] = f2bf(f[10] * scale * g2.z); o1[3] = f2bf(f[11] * scale * g2.w);
  o1[4] = f2bf(f[12] * scale * g3.x); o1[5] = f2bf(f[13] * scale * g3.y);
  o1[6] = f2bf(f[14] * scale * g3.z); o1[7] = f2bf(f[15] * scale * g3.w);
  *(ushort8*)&p[base] = o0;
  *(ushort8*)&p[base + 8] = o1;
}

// ---------- launch ----------
extern "C" void kernel_launch(void* const* d_in, const int* in_sizes, int n_in,
                              void* d_out, int out_size, void* d_ws, size_t ws_size,
                              hipStream_t stream) {
  const float* x  = (const float*)d_in[0];
  const float* W1 = (const float*)d_in[1];
  const float* W2 = (const float*)d_in[2];
  const float* D  = (const float*)d_in[3];
  const float* g  = (const float*)d_in[4];
  const int M = 8192, K = 4096, N = 4096;

  // workspace layout (bytes): xb 64MB | w1t 32MB | w2t 32MB | h 64MB  = 192MB
  char* ws = (char*)d_ws;
  unsigned short* xb  = (unsigned short*)ws;
  unsigned short* w1t = (unsigned short*)(ws + (size_t)M * K * 2);
  unsigned short* w2t = (unsigned short*)(ws + (size_t)M * K * 2 + (size_t)K * N * 2);
  unsigned short* h   = (unsigned short*)(ws + (size_t)M * K * 2 + (size_t)2 * K * N * 2);

  // 1. x -> bf16
  int n8 = (M * K) / 8;
  k_cvt_bf16<<<n8 / 256, 256, 0, stream>>>(x, xb, n8);
  // 2. W1 (K x N) -> w1t (N x K) bf16 ;  W2 (N x K) -> w2t (K x N) bf16
  k_transpose_cvt<<<dim3(N / 64, K / 64), 256, 0, stream>>>(W1, w1t, K, N);
  k_transpose_cvt<<<dim3(K / 64, N / 64), 256, 0, stream>>>(W2, w2t, N, K);
  // 3. h = x @ W1 + D  (bf16 out to ws)
  k_gemm<1><<<(M / 128) * (N / 128), 256, 0, stream>>>(xb, w1t, D, (void*)h, M, N, K);
  // 4. h = rmsnorm(h) * g, in place
  k_rmsnorm<<<M, 256, 0, stream>>>(h, g, N);
  // 5. out = h @ W2 + D  (f32 to d_out)
  k_gemm<0><<<(M / 128) * (K / 128), 256, 0, stream>>>(h, w2t, D, d_out, M, K, N);
}

// Round 2
// 1294.722 us; speedup vs baseline: 1.0140x; 1.0140x over previous
//
#include <hip/hip_runtime.h>
#include <hip/hip_bf16.h>

// ---------- types ----------
typedef float f32x4 __attribute__((ext_vector_type(4)));
typedef short short8 __attribute__((ext_vector_type(8)));
typedef unsigned short ushort8 __attribute__((ext_vector_type(8)));
typedef unsigned short ushort4v __attribute__((ext_vector_type(4)));

static __device__ __forceinline__ unsigned short f2bf(float f) {
  unsigned u = __builtin_bit_cast(unsigned, f);
  u += 0x7fffu + ((u >> 16) & 1u);
  return (unsigned short)(u >> 16);
}
static __device__ __forceinline__ float bf2f(unsigned short s) {
  return __builtin_bit_cast(float, (unsigned)s << 16);
}

// ---------- 1. f32 -> bf16 convert (x) ----------
__global__ __launch_bounds__(256) void k_cvt_bf16(const float* __restrict__ in,
                                                  unsigned short* __restrict__ out,
                                                  int n8) {
  int i = blockIdx.x * 256 + threadIdx.x;
  if (i >= n8) return;
  const float4* p = (const float4*)in + (size_t)i * 2;
  float4 a = p[0], b = p[1];
  ushort8 o;
  o[0] = f2bf(a.x); o[1] = f2bf(a.y); o[2] = f2bf(a.z); o[3] = f2bf(a.w);
  o[4] = f2bf(b.x); o[5] = f2bf(b.y); o[6] = f2bf(b.z); o[7] = f2bf(b.w);
  *(ushort8*)(out + (size_t)i * 8) = o;
}

// ---------- 2. f32 [R][C] -> bf16 [C][R] transpose+convert ----------
__global__ __launch_bounds__(256) void k_transpose_cvt(const float* __restrict__ in,
                                                       unsigned short* __restrict__ out,
                                                       int R, int C) {
  __shared__ float tile[64][65];
  int c0 = blockIdx.x * 64;
  int r0 = blockIdx.y * 64;
  int t = threadIdx.x;
  int tr = t >> 4;
  int tc = (t & 15) << 2;
  for (int i = 0; i < 4; ++i) {
    int r = tr + (i << 4);
    float4 v = *(const float4*)&in[(size_t)(r0 + r) * C + c0 + tc];
    tile[r][tc] = v.x; tile[r][tc + 1] = v.y; tile[r][tc + 2] = v.z; tile[r][tc + 3] = v.w;
  }
  __syncthreads();
  for (int i = 0; i < 4; ++i) {
    int c = tr + (i << 4);
    ushort4v o;
    o[0] = f2bf(tile[tc + 0][c]);
    o[1] = f2bf(tile[tc + 1][c]);
    o[2] = f2bf(tile[tc + 2][c]);
    o[3] = f2bf(tile[tc + 3][c]);
    *(ushort4v*)&out[(size_t)(c0 + c) * R + r0 + tc] = o;
  }
}

// ---------- 3. bf16 GEMM: 256x256 tile, BK=64, 8 waves, 8-phase schedule ----------
// A:  M x K bf16 row-major; Bt: N x K bf16 row-major (= B^T); out = A*B + D
// LDS 128KiB: [buf0 A 32K][buf0 B 32K][buf1 A 32K][buf1 B 32K]
// st_16x32 swizzle: byte ^= ((byte>>9)&1)<<5  (applied on read AND on the
// pre-swizzled global source of the linear-dest global_load_lds)

#define LDSW(off) ({ int _o = (off); _o ^= ((_o >> 9) & 1) << 5; \
                     *(const short8*)((const char*)lds + _o); })

#define RD_A(cur, half) do { \
  _Pragma("unroll") for (int i_ = 0; i_ < 4; ++i_) { \
    _Pragma("unroll") for (int ks_ = 0; ks_ < 2; ++ks_) \
      a[i_][ks_] = LDSW((cur) + abase + ((half) * 64 + i_ * 16) * 128 + ks_ * 64); } \
} while (0)

#define RD_B(cur, j0) do { \
  _Pragma("unroll") for (int j_ = 0; j_ < 2; ++j_) { \
    _Pragma("unroll") for (int ks_ = 0; ks_ < 2; ++ks_) \
      b[(j0) + j_][ks_] = LDSW((cur) + bbase + ((j0) + j_) * 2048 + ks_ * 64); } \
} while (0)

#define MMQ(i0, j0) do { \
  _Pragma("unroll") for (int di_ = 0; di_ < 4; ++di_) { \
    _Pragma("unroll") for (int dj_ = 0; dj_ < 2; ++dj_) { \
      _Pragma("unroll") for (int ks_ = 0; ks_ < 2; ++ks_) \
        acc[(i0) + di_][(j0) + dj_] = __builtin_amdgcn_mfma_f32_16x16x32_bf16( \
            a[di_][ks_], b[(j0) + dj_][ks_], acc[(i0) + di_][(j0) + dj_], 0, 0, 0); } } \
} while (0)

#define STG(ptr, T, base, h) do { \
  __builtin_amdgcn_global_load_lds( \
      (const __attribute__((address_space(1))) void*)((ptr) + (size_t)(T) * 64 + soff[2 * (h)]), \
      (__attribute__((address_space(3))) void*)((char*)lds + (base) + reld[2 * (h)]), 16, 0, 0); \
  __builtin_amdgcn_global_load_lds( \
      (const __attribute__((address_space(1))) void*)((ptr) + (size_t)(T) * 64 + soff[2 * (h) + 1]), \
      (__attribute__((address_space(3))) void*)((char*)lds + (base) + reld[2 * (h) + 1]), 16, 0, 0); \
} while (0)

#define PBAR() __builtin_amdgcn_s_barrier()
#define LGKM0() asm volatile("s_waitcnt lgkmcnt(0)" ::: "memory")
#define VMW4() asm volatile("s_waitcnt vmcnt(4)" ::: "memory")
#define VMW0() asm volatile("s_waitcnt vmcnt(0)" ::: "memory")

template <int OUT_BF16>
__global__ __launch_bounds__(512, 2) void k_gemm256(const unsigned short* __restrict__ A,
                                                    const unsigned short* __restrict__ Bt,
                                                    const float* __restrict__ D,
                                                    void* __restrict__ out,
                                                    int M, int N, int K) {
  __shared__ unsigned short lds[65536];  // 128 KiB

  int nwg = gridDim.x;
  int bid = blockIdx.x;
  int cpx = nwg >> 3;
  int swz = (bid & 7) * cpx + (bid >> 3);
  int nbn = N >> 8;
  int bm0 = (swz / nbn) << 8;
  int bn0 = (swz % nbn) << 8;

  int tid = threadIdx.x;
  int lane = tid & 63;
  int w = tid >> 6;
  int wr = w >> 2, wc = w & 3;  // 2 x 4 waves; per-wave output 128 x 64

  const unsigned short* pA = A + (size_t)bm0 * K;
  const unsigned short* pB = Bt + (size_t)bn0 * K;

  // staging offsets: combos c = h*2+s; linear LDS dest rel, inverse-swizzled global src
  size_t soff[4];
  int reld[4];
#pragma unroll
  for (int c = 0; c < 4; ++c) {
    int rel = ((c >> 1) << 14) + ((c & 1) << 13) + tid * 16;
    int u = rel ^ (((rel >> 9) & 1) << 5);
    soff[c] = (size_t)(u >> 7) * K + ((u & 127) >> 1);
    reld[c] = rel;
  }

  int laneRow = lane & 15;
  int laneKb = (lane >> 4) << 4;
  int abase = (wr * 128 + laneRow) * 128 + laneKb;
  int bbase = 32768 + (wc * 64 + laneRow) * 128 + laneKb;

  f32x4 acc[8][4];
#pragma unroll
  for (int i = 0; i < 8; ++i)
#pragma unroll
    for (int j = 0; j < 4; ++j)
      acc[i][j] = f32x4{0.f, 0.f, 0.f, 0.f};

  short8 a[4][2], b[4][2];

  const int NT = K >> 6;  // K-tiles of 64

  // prologue: tile0 B0,B1,A0,A1 ; tile1 B0,B1 -> wait tile0 complete
  STG(pB, 0, 32768, 0); STG(pB, 0, 32768, 1);
  STG(pA, 0, 0, 0);     STG(pA, 0, 0, 1);
  STG(pB, 1, 98304, 0); STG(pB, 1, 98304, 1);
  VMW4();
  PBAR();

  int T = 0;
  for (; T < NT - 2; T += 2) {
    // ---- tile T (buf0: A@0, B@32768) ----
    RD_A(0, 0); RD_B(0, 0);
    STG(pA, T + 1, 65536, 0);
    PBAR(); LGKM0(); __builtin_amdgcn_s_setprio(1); MMQ(0, 0); __builtin_amdgcn_s_setprio(0); PBAR();

    RD_B(0, 2);
    STG(pA, T + 1, 65536, 1);
    PBAR(); LGKM0(); __builtin_amdgcn_s_setprio(1); MMQ(0, 2); __builtin_amdgcn_s_setprio(0); PBAR();

    RD_A(0, 1);
    STG(pB, T + 2, 32768, 0);
    PBAR(); LGKM0(); __builtin_amdgcn_s_setprio(1); MMQ(4, 2); __builtin_amdgcn_s_setprio(0); PBAR();

    STG(pB, T + 2, 32768, 1);
    VMW4();
    PBAR(); __builtin_amdgcn_s_setprio(1); MMQ(4, 0); __builtin_amdgcn_s_setprio(0); PBAR();

    // ---- tile T+1 (buf1: A@65536, B@98304) ----
    RD_A(65536, 0); RD_B(65536, 0);
    STG(pA, T + 2, 0, 0);
    PBAR(); LGKM0(); __builtin_amdgcn_s_setprio(1); MMQ(0, 0); __builtin_amdgcn_s_setprio(0); PBAR();

    RD_B(65536, 2);
    STG(pA, T + 2, 0, 1);
    PBAR(); LGKM0(); __builtin_amdgcn_s_setprio(1); MMQ(0, 2); __builtin_amdgcn_s_setprio(0); PBAR();

    RD_A(65536, 1);
    STG(pB, T + 3, 98304, 0);
    PBAR(); LGKM0(); __builtin_amdgcn_s_setprio(1); MMQ(4, 2); __builtin_amdgcn_s_setprio(0); PBAR();

    STG(pB, T + 3, 98304, 1);
    VMW4();
    PBAR(); __builtin_amdgcn_s_setprio(1); MMQ(4, 0); __builtin_amdgcn_s_setprio(0); PBAR();
  }

  // ---- final pair: tile NT-2 (buf0), tile NT-1 (buf1) ----
  RD_A(0, 0); RD_B(0, 0);
  STG(pA, T + 1, 65536, 0);
  PBAR(); LGKM0(); __builtin_amdgcn_s_setprio(1); MMQ(0, 0); __builtin_amdgcn_s_setprio(0); PBAR();
  RD_B(0, 2);
  STG(pA, T + 1, 65536, 1);
  PBAR(); LGKM0(); __builtin_amdgcn_s_setprio(1); MMQ(0, 2); __builtin_amdgcn_s_setprio(0); PBAR();
  RD_A(0, 1);
  PBAR(); LGKM0(); __builtin_amdgcn_s_setprio(1); MMQ(4, 2); __builtin_amdgcn_s_setprio(0); PBAR();
  VMW0();
  PBAR(); __builtin_amdgcn_s_setprio(1); MMQ(4, 0); __builtin_amdgcn_s_setprio(0); PBAR();

  RD_A(65536, 0); RD_B(65536, 0);
  PBAR(); LGKM0(); __builtin_amdgcn_s_setprio(1); MMQ(0, 0); __builtin_amdgcn_s_setprio(0); PBAR();
  RD_B(65536, 2);
  PBAR(); LGKM0(); __builtin_amdgcn_s_setprio(1); MMQ(0, 2); __builtin_amdgcn_s_setprio(0); PBAR();
  RD_A(65536, 1);
  PBAR(); LGKM0(); __builtin_amdgcn_s_setprio(1); MMQ(4, 2); __builtin_amdgcn_s_setprio(0); PBAR();
  MMQ(4, 0);

  // ---- epilogue: + D, store (C/D layout: col=lane&15, row=(lane>>4)*4+reg) ----
  int er = bm0 + wr * 128 + ((lane >> 4) << 2);
  int ec = bn0 + wc * 64 + laneRow;
#pragma unroll
  for (int i = 0; i < 8; ++i) {
#pragma unroll
    for (int j = 0; j < 4; ++j) {
      int r = er + i * 16;
      int c = ec + j * 16;
#pragma unroll
      for (int rr = 0; rr < 4; ++rr) {
        size_t idx = (size_t)(r + rr) * N + c;
        float v = acc[i][j][rr] + D[idx];
        if (OUT_BF16)
          ((unsigned short*)out)[idx] = f2bf(v);
        else
          ((float*)out)[idx] = v;
      }
    }
  }
}

// ---------- 4. row RMSNorm in-place on bf16 h, scale by g ----------
__global__ __launch_bounds__(256) void k_rmsnorm(unsigned short* __restrict__ h,
                                                 const float* __restrict__ g,
                                                 int N) {
  __shared__ float red[4];
  int rowi = blockIdx.x;
  unsigned short* p = h + (size_t)rowi * N;
  int t = threadIdx.x;
  int base = t << 4;
  ushort8 v0 = *(const ushort8*)&p[base];
  ushort8 v1 = *(const ushort8*)&p[base + 8];
  float f[16];
  float ss = 0.f;
  for (int j = 0; j < 8; ++j) { f[j] = bf2f(v0[j]); ss += f[j] * f[j]; }
  for (int j = 0; j < 8; ++j) { f[8 + j] = bf2f(v1[j]); ss += f[8 + j] * f[8 + j]; }
  for (int off = 32; off > 0; off >>= 1) ss += __shfl_xor(ss, off);
  if ((t & 63) == 0) red[t >> 6] = ss;
  __syncthreads();
  float total = red[0] + red[1] + red[2] + red[3];
  float scale = rsqrtf(total / (float)N + 1e-6f);
  float4 g0 = *(const float4*)&g[base];
  float4 g1 = *(const float4*)&g[base + 4];
  float4 g2 = *(const float4*)&g[base + 8];
  float4 g3 = *(const float4*)&g[base + 12];
  ushort8 o0, o1;
  o0[0] = f2bf(f[0] * scale * g0.x);  o0[1] = f2bf(f[1] * scale * g0.y);
  o0[2] = f2bf(f[2] * scale * g0.z);  o0[3] = f2bf(f[3] * scale * g0.w);
  o0[4] = f2bf(f[4] * scale * g1.x);  o0[5] = f2bf(f[5] * scale * g1.y);
  o0[6] = f2bf(f[6] * scale * g1.z);  o0[7] = f2bf(f[7] * scale * g1.w);
  o1[0] = f2bf(f[8] * scale * g2.x);  o1[1] = f2bf(f[9] * scale * g2.y);
  o1[2] = f2bf(f[10] * scale * g2.z); o1[3] = f2bf(f[11] * scale * g2.w);
  o1[4] = f2bf(f[12] * scale * g3.x); o1[5] = f2bf(f[13] * scale * g3.y);
  o1[6] = f2bf(f[14] * scale * g3.z); o1[7] = f2bf(f[15] * scale * g3.w);
  *(ushort8*)&p[base] = o0;
  *(ushort8*)&p[base + 8] = o1;
}

// ---------- launch ----------
extern "C" void kernel_launch(void* const* d_in, const int* in_sizes, int n_in,
                              void* d_out, int out_size, void* d_ws, size_t ws_size,
                              hipStream_t stream) {
  const float* x  = (const float*)d_in[0];
  const float* W1 = (const float*)d_in[1];
  const float* W2 = (const float*)d_in[2];
  const float* D  = (const float*)d_in[3];
  const float* g  = (const float*)d_in[4];
  const int M = 8192, K = 4096, N = 4096;

  char* ws = (char*)d_ws;
  unsigned short* xb  = (unsigned short*)ws;
  unsigned short* w1t = (unsigned short*)(ws + (size_t)M * K * 2);
  unsigned short* w2t = (unsigned short*)(ws + (size_t)M * K * 2 + (size_t)K * N * 2);
  unsigned short* h   = (unsigned short*)(ws + (size_t)M * K * 2 + (size_t)2 * K * N * 2);

  int n8 = (M * K) / 8;
  k_cvt_bf16<<<n8 / 256, 256, 0, stream>>>(x, xb, n8);
  k_transpose_cvt<<<dim3(N / 64, K / 64), 256, 0, stream>>>(W1, w1t, K, N);
  k_transpose_cvt<<<dim3(K / 64, N / 64), 256, 0, stream>>>(W2, w2t, N, K);
  k_gemm256<1><<<(M / 256) * (N / 256), 512, 0, stream>>>(xb, w1t, D, (void*)h, M, N, K);
  k_rmsnorm<<<M, 256, 0, stream>>>(h, g, N);
  k_gemm256<0><<<(M / 256) * (K / 256), 512, 0, stream>>>(h, w2t, D, d_out, M, K, N);
}